// Round 14
// baseline (324.237 us; speedup 1.0000x reference)
//
#include <hip/hip_runtime.h>
#include <math.h>

// Problem constants: B=4, Cin=64, H=W=160, K=3, pad=1, stride=1, Cout=64
#define B_   4
#define CIN  64
#define H_   160
#define W_   160
#define COUT 64
#define OFFC 27            // 27 offset-conv output channels
#define HW_  (H_ * W_)     // 25600
#define NPIX (B_ * HW_)    // 102400

#define TILE_P 64          // pixels per k_dcn block (64 | HW_)
#define VP2    65          // vals pitch: odd -> all LDS phases 2-way (free; R13: 230K conflicts, minor)

// Workspace (floats):
//   Tier A (ws >= 37.4 MB): x_nhwc[NPIX*64] | om2[27*NPIX] | wT[576*64]
//   Tier B (ws >= 11.2 MB):                   om2[27*NPIX] | wT[576*64]
// om2 PLANE-MAJOR: om2[o*NPIX + p]

// ---------------------------------------------------------------------------
// Kernel 0a: NCHW -> NHWC transpose of the input via LDS tiles.
// ---------------------------------------------------------------------------
__global__ __launch_bounds__(256) void k_transpose_nhwc(const float* __restrict__ in,
                                                        float* __restrict__ out) {
    __shared__ float tile[CIN][33];
    int blk = blockIdx.x;           // b*H*5 + y*5 + wc
    int wc  = blk % 5;
    int by  = blk / 5;
    int y   = by % H_;
    int b   = by / H_;
    int w0  = wc * 32;
    int t   = threadIdx.x;

    int wi = t & 31, ch = t >> 5;
#pragma unroll
    for (int r = 0; r < 8; ++r) {
        int c = r * 8 + ch;
        tile[c][wi] = in[((b * CIN + c) * H_ + y) * W_ + w0 + wi];
    }
    __syncthreads();
    int c2 = t & 63, wj = t >> 6;
#pragma unroll
    for (int r = 0; r < 8; ++r) {
        int wi2 = r * 4 + wj;
        out[((b * H_ + y) * W_ + w0 + wi2) * CIN + c2] = tile[c2][wi2];
    }
}

// ---------------------------------------------------------------------------
// Kernel 0b: w_dcn (Cout,Cin,3,3) -> wT[(k*64 + c)*64 + co]
// ---------------------------------------------------------------------------
__global__ void k_transpose_w(const float* __restrict__ w, float* __restrict__ wT) {
    int i  = blockIdx.x * 256 + threadIdx.x;
    int co = i & 63;
    int kc = i >> 6;
    int c  = kc & 63;
    int k  = kc >> 6;
    wT[i] = w[(co * CIN + c) * 9 + k];
}

// ---------------------------------------------------------------------------
// Kernel A (v2 restored): offset conv, 3 groups of 9 outs. R8 measured the
// v2 form inside a 328us total with others=136us; R13's 2-plane interleave
// (v3) correlated with others=168us -> revert to the measured-better v2 loop.
// ---------------------------------------------------------------------------
__global__ __launch_bounds__(256, 4) void k_offconv(const float* __restrict__ in,
                                                    const float* __restrict__ wo,
                                                    const float* __restrict__ bo,
                                                    float* __restrict__ om2) {
    int bid = (int)blockIdx.x;                 // 0..1199
    int id  = (bid & 7) * 150 + (bid >> 3);    // XCD swizzle (1200 = 8*150)
    int g   = id % 3;                          // output group
    int pb  = id / 3;                          // pixel block 0..399
    int p   = pb * 256 + threadIdx.x;
    int b   = p / HW_;
    int rem = p - b * HW_;
    int y   = rem / W_;
    int x   = rem - y * W_;

    int   off[9];
    float valid[9];
#pragma unroll
    for (int di = 0; di < 3; ++di) {
        int yy = y + di - 1;
        int yc = min(max(yy, 0), H_ - 1);
        bool yok = (yy >= 0) & (yy < H_);
#pragma unroll
        for (int dj = 0; dj < 3; ++dj) {
            int xx = x + dj - 1;
            int xc = min(max(xx, 0), W_ - 1);
            bool ok = yok & (xx >= 0) & (xx < W_);
            off[di * 3 + dj]   = yc * W_ + xc;
            valid[di * 3 + dj] = ok ? 1.f : 0.f;
        }
    }

    float acc[9];
#pragma unroll
    for (int j = 0; j < 9; ++j) acc[j] = bo[g * 9 + j];

    const float* inb = in + (size_t)b * CIN * HW_;
    const float* wg  = wo + (size_t)(g * 9) * 576;
#pragma unroll 2
    for (int c = 0; c < CIN; ++c) {
        float v[9];
#pragma unroll
        for (int tp = 0; tp < 9; ++tp)
            v[tp] = inb[c * HW_ + off[tp]] * valid[tp];
#pragma unroll
        for (int j = 0; j < 9; ++j) {
#pragma unroll
            for (int tp = 0; tp < 9; ++tp)
                acc[j] += v[tp] * wg[j * 576 + c * 9 + tp];
        }
    }
#pragma unroll
    for (int j = 0; j < 9; ++j)
        om2[(size_t)(g * 9 + j) * NPIX + p] = acc[j];       // coalesced
}

// ---------------------------------------------------------------------------
// Kernel B v4: pipelined sampling+GEMM. R13: 152us, VALUBusy 61%, occ 47%,
// conflicts 230K -> residual 39% is barrier drain (3 barriers/tap, no
// stage/compute overlap). v4:
//   * sk_all[9][64][8] computed ONCE up front (18KB) -> no per-tap sk barrier
//   * vals double-buffered (2 x 64 x VP2 = 33.3KB)
//   * per tap: { stage(k+1)->buf^1 ; compute(k)<-buf ; ONE barrier }
//     -> 11 barriers total (was 27+); waves overlap stage gathers with
//     sibling-wave compute FMAs inside the block.
// LDS 51.7KB -> 3 blocks/CU (12 waves). VGPR ~50 (LB(256,3)).
// ---------------------------------------------------------------------------
template <bool NHWC>
__global__ __launch_bounds__(256, 3) void k_dcn(const float* __restrict__ xsrc,
                                                const float* __restrict__ om2,
                                                const float* __restrict__ wT,
                                                const float* __restrict__ bd,
                                                float* __restrict__ out) {
    __shared__ __align__(16) float sk[9 * TILE_P * 8];   // 18,432 B: all 9 taps
    __shared__ __align__(16) float vals[2][64 * VP2];    // 33,280 B (buf0 reused as outs)

    int t   = threadIdx.x;
    int bid = (int)blockIdx.x;
    int blk = (bid & 7) * ((NPIX / TILE_P) / 8) + (bid >> 3); // 1600 = 8*200
    int p0  = blk * TILE_P;
    int b   = p0 / HW_;          // uniform per block (64 | 25600)
    int rb  = p0 - b * HW_;

    int lane = t & 63;
    int co0  = __builtin_amdgcn_readfirstlane((t >> 6) << 4); // wave-uniform cout base

    float acc[16];
#pragma unroll
    for (int j = 0; j < 16; ++j) acc[j] = bd[co0 + j];

    const float* base = xsrc + (size_t)b * CIN * HW_;

    // ---- setup ALL taps once: e = tap*64 + pix ---------------------------
#pragma unroll
    for (int it = 0; it < 3; ++it) {
        int e = t + it * 256;
        if (e < 9 * TILE_P) {
            int k   = e >> 6;            // wave-uniform (64 | boundaries)
            int pix = e & 63;
            int p   = p0 + pix;
            int rem = rb + pix;
            int y   = rem / W_;
            int x   = rem - y * W_;
            float oy = om2[(size_t)(2 * k) * NPIX + p];      // coalesced
            float ox = om2[(size_t)(2 * k + 1) * NPIX + p];
            float mr = om2[(size_t)(18 + k) * NPIX + p];
            float m  = 1.f / (1.f + expf(-mr));
            int ki = k / 3, kj = k - ki * 3;
            float fy  = (float)(y - 1 + ki) + oy;
            float fx  = (float)(x - 1 + kj) + ox;
            float fy0 = floorf(fy), fx0 = floorf(fx);
            float dy = fy - fy0, dx = fx - fx0;
            int iy = (int)fy0, ix = (int)fx0;
            bool yok0 = (iy >= 0) & (iy < H_);
            bool yok1 = (iy + 1 >= 0) & (iy + 1 < H_);
            bool xok0 = (ix >= 0) & (ix < W_);
            bool xok1 = (ix + 1 >= 0) & (ix + 1 < W_);
            int iyc0 = min(max(iy, 0), H_ - 1);
            int iyc1 = min(max(iy + 1, 0), H_ - 1);
            int ixc0 = min(max(ix, 0), W_ - 1);
            int ixc1 = min(max(ix + 1, 0), W_ - 1);
            const int mul = NHWC ? 64 : 1;
            float4 swt, sof;
            swt.x = (1.f - dy) * (1.f - dx) * m * (float)(yok0 & xok0);
            swt.y = (1.f - dy) * dx         * m * (float)(yok0 & xok1);
            swt.z = dy * (1.f - dx)         * m * (float)(yok1 & xok0);
            swt.w = dy * dx                 * m * (float)(yok1 & xok1);
            sof.x = __int_as_float((iyc0 * W_ + ixc0) * mul);
            sof.y = __int_as_float((iyc0 * W_ + ixc1) * mul);
            sof.z = __int_as_float((iyc1 * W_ + ixc0) * mul);
            sof.w = __int_as_float((iyc1 * W_ + ixc1) * mul);
            *reinterpret_cast<float4*>(sk + e * 8)     = swt;
            *reinterpret_cast<float4*>(sk + e * 8 + 4) = sof;
        }
    }
    __syncthreads(); // sk_all ready

    int cterm = NHWC ? lane : lane * HW_;

    // ---- prologue: stage tap 0 into buf 0 --------------------------------
#pragma unroll 4
    for (int it = 0; it < 16; ++it) {
        int pix = (t >> 6) + 4 * it;                 // wave-uniform
        const float* s = sk + pix * 8;               // tap 0
        float4 sw = *reinterpret_cast<const float4*>(s);
        float4 so = *reinterpret_cast<const float4*>(s + 4);
        float g00 = base[__float_as_int(so.x) + cterm];
        float g01 = base[__float_as_int(so.y) + cterm];
        float g10 = base[__float_as_int(so.z) + cterm];
        float g11 = base[__float_as_int(so.w) + cterm];
        vals[0][lane * VP2 + pix] = g00 * sw.x + g01 * sw.y + g10 * sw.z + g11 * sw.w;
    }
    __syncthreads(); // vals[0] ready

    // ---- pipelined main loop: stage(k+1) || compute(k), 1 barrier/tap ----
    for (int k = 0; k < 9; ++k) {
        int cur = k & 1;

        if (k < 8) {
            // stage tap k+1 into buf cur^1 (no hazard with compute(k))
            const float* skt = sk + (k + 1) * TILE_P * 8;
            float* vb = vals[cur ^ 1];
#pragma unroll 4
            for (int it = 0; it < 16; ++it) {
                int pix = (t >> 6) + 4 * it;
                const float* s = skt + pix * 8;
                float4 sw = *reinterpret_cast<const float4*>(s);
                float4 so = *reinterpret_cast<const float4*>(s + 4);
                float g00 = base[__float_as_int(so.x) + cterm];
                float g01 = base[__float_as_int(so.y) + cterm];
                float g10 = base[__float_as_int(so.z) + cterm];
                float g11 = base[__float_as_int(so.w) + cterm];
                vb[lane * VP2 + pix] = g00 * sw.x + g01 * sw.y + g10 * sw.z + g11 * sw.w;
            }
        }

        // compute(k) from buf cur
        const float* va = vals[cur];
        const float* wk = wT + (k * 64) * 64 + co0;
#pragma unroll 4
        for (int c = 0; c < 64; ++c) {
            float v = va[c * VP2 + lane];            // 2-way (free)
            const float* wp = wk + c * 64;           // wave-uniform -> s_load
            float4 wv0 = *reinterpret_cast<const float4*>(wp);
            float4 wv1 = *reinterpret_cast<const float4*>(wp + 4);
            float4 wv2 = *reinterpret_cast<const float4*>(wp + 8);
            float4 wv3 = *reinterpret_cast<const float4*>(wp + 12);
            acc[0]  += v * wv0.x;  acc[1]  += v * wv0.y;
            acc[2]  += v * wv0.z;  acc[3]  += v * wv0.w;
            acc[4]  += v * wv1.x;  acc[5]  += v * wv1.y;
            acc[6]  += v * wv1.z;  acc[7]  += v * wv1.w;
            acc[8]  += v * wv2.x;  acc[9]  += v * wv2.y;
            acc[10] += v * wv2.z;  acc[11] += v * wv2.w;
            acc[12] += v * wv3.x;  acc[13] += v * wv3.y;
            acc[14] += v * wv3.z;  acc[15] += v * wv3.w;
        }
        __syncthreads(); // vals[cur^1] ready for compute(k+1); vals[cur] free
    }

    // ---- Epilogue: transpose via vals[0] -> coalesced NCHW stores --------
#pragma unroll
    for (int j = 0; j < 16; ++j)
        vals[0][(co0 + j) * VP2 + lane] = acc[j];    // 2-way (free)
    __syncthreads();
#pragma unroll 4
    for (int it = 0; it < 16; ++it) {
        int i  = t + it * 256;
        int co = i >> 6;             // wave-uniform per iter
        int px = i & 63;             // 64 consecutive -> 256B stores
        out[((size_t)(b * COUT + co)) * HW_ + rb + px] = vals[0][co * VP2 + px];
    }
}

extern "C" void kernel_launch(void* const* d_in, const int* in_sizes, int n_in,
                              void* d_out, int out_size, void* d_ws, size_t ws_size,
                              hipStream_t stream) {
    const float* input = (const float*)d_in[0]; // (4,64,160,160)
    const float* w_off = (const float*)d_in[1]; // (27,64,3,3)
    const float* b_off = (const float*)d_in[2]; // (27,)
    const float* w_dcn = (const float*)d_in[3]; // (64,64,3,3)
    const float* b_dcn = (const float*)d_in[4]; // (64,)
    float* out = (float*)d_out;                 // (4,64,160,160)

    const size_t XN_F = (size_t)NPIX * CIN;
    const size_t OM_F = (size_t)NPIX * OFFC;
    const size_t WT_F = 576 * 64;
    const size_t need_full = (XN_F + OM_F + WT_F) * sizeof(float);

    float* ws = (float*)d_ws;
    if (ws_size >= need_full) {
        float* x_nhwc = ws;
        float* om2    = ws + XN_F;
        float* wT     = om2 + OM_F;
        k_transpose_nhwc<<<dim3(B_ * H_ * 5), dim3(256), 0, stream>>>(input, x_nhwc);
        k_transpose_w<<<dim3(144), dim3(256), 0, stream>>>(w_dcn, wT);
        k_offconv<<<dim3(1200), dim3(256), 0, stream>>>(input, w_off, b_off, om2);
        k_dcn<true><<<dim3(NPIX / TILE_P), dim3(256), 0, stream>>>(x_nhwc, om2, wT, b_dcn, out);
    } else {
        float* om2 = ws;
        float* wT  = om2 + OM_F;
        k_transpose_w<<<dim3(144), dim3(256), 0, stream>>>(w_dcn, wT);
        k_offconv<<<dim3(1200), dim3(256), 0, stream>>>(input, w_off, b_off, om2);
        k_dcn<false><<<dim3(NPIX / TILE_P), dim3(256), 0, stream>>>(input, om2, wT, b_dcn, out);
    }
}